// Round 1
// baseline (113.688 us; speedup 1.0000x reference)
//
#include <hip/hip_runtime.h>

#define IN_CH 256
#define OUT_CH 256
#define N_TASKS 64
#define W_SIZE (OUT_CH * IN_CH)          // 65536
#define FULL_EMBED (W_SIZE + OUT_CH)     // 65792
#define OTILE 32                         // outputs per block
#define NBLK_O (OUT_CH / OTILE)          // 8 out-tiles
#define THREADS 512
#define O_PER_WAVE (OTILE / (THREADS / 64))  // 4 outputs per wave

__global__ __launch_bounds__(THREADS, 2) void mtal_kernel(
    const float* __restrict__ x, const int* __restrict__ tids,
    const float* __restrict__ emb, float* __restrict__ out, int B)
{
    __shared__ int rows[4096];
    __shared__ int cnt;

    const int t   = blockIdx.x >> 3;   // task id
    const int ot  = blockIdx.x & 7;    // out-tile
    const int tid = threadIdx.x;

    if (tid == 0) cnt = 0;
    __syncthreads();

    // Gather rows belonging to task t (order irrelevant).
    for (int i = tid; i < B; i += THREADS) {
        if (tids[i] == t) {
            int p = atomicAdd(&cnt, 1);
            rows[p] = i;
        }
    }
    __syncthreads();

    const int n = __builtin_amdgcn_readfirstlane(cnt);
    if (n == 0) return;

    const int lane  = tid & 63;
    // Force wave-uniformity so W/bias loads become s_load (SGPR-resident W).
    const int w     = __builtin_amdgcn_readfirstlane(tid >> 6);
    const int obase = ot * OTILE + w * O_PER_WAVE;

    const float* __restrict__ wbase = emb + (size_t)t * FULL_EMBED;

    float bias[O_PER_WAVE];
#pragma unroll
    for (int j = 0; j < O_PER_WAVE; ++j)
        bias[j] = wbase[W_SIZE + obase + j];

    for (int r0 = 0; r0 < n; r0 += 64) {
        const int  ridx  = r0 + lane;
        const bool valid = ridx < n;
        const int  row   = rows[valid ? ridx : 0];   // safe dup for idle lanes
        const float* __restrict__ xr = x + (size_t)row * IN_CH;

        float acc[O_PER_WAVE];
#pragma unroll
        for (int j = 0; j < O_PER_WAVE; ++j) acc[j] = bias[j];

        for (int kc = 0; kc < IN_CH; kc += 32) {
            float4 xv[8];
#pragma unroll
            for (int u = 0; u < 8; ++u)
                xv[u] = *reinterpret_cast<const float4*>(xr + kc + 4 * u);
#pragma unroll
            for (int j = 0; j < O_PER_WAVE; ++j) {
                const float* __restrict__ wr =
                    wbase + (size_t)(obase + j) * IN_CH + kc;
#pragma unroll
                for (int u = 0; u < 8; ++u) {
                    acc[j] += wr[4 * u + 0] * xv[u].x;
                    acc[j] += wr[4 * u + 1] * xv[u].y;
                    acc[j] += wr[4 * u + 2] * xv[u].z;
                    acc[j] += wr[4 * u + 3] * xv[u].w;
                }
            }
        }

        if (valid) {
            float4 res = make_float4(acc[0], acc[1], acc[2], acc[3]);
            *reinterpret_cast<float4*>(out + (size_t)row * OUT_CH + obase) = res;
        }
    }
}

extern "C" void kernel_launch(void* const* d_in, const int* in_sizes, int n_in,
                              void* d_out, int out_size, void* d_ws, size_t ws_size,
                              hipStream_t stream) {
    const float* x    = (const float*)d_in[0];
    const int*   tids = (const int*)d_in[1];
    const float* emb  = (const float*)d_in[2];
    float*       out  = (float*)d_out;
    const int B = in_sizes[1];   // 4096

    mtal_kernel<<<dim3(N_TASKS * NBLK_O), dim3(THREADS), 0, stream>>>(
        x, tids, emb, out, B);
}

// Round 2
// 85.432 us; speedup vs baseline: 1.3307x; 1.3307x over previous
//
#include <hip/hip_runtime.h>
#include <hip/hip_bf16.h>

#define IN_CH 256
#define OUT_CH 256
#define N_TASKS 64
#define W_SIZE (OUT_CH * IN_CH)          // 65536
#define FULL_EMBED (W_SIZE + OUT_CH)     // 65792
#define THREADS 256
#define MAXB 4096
#define NCOLT 16                         // col tiles of 16 outputs

typedef __attribute__((ext_vector_type(8))) short bf16x8;
typedef __attribute__((ext_vector_type(4))) float f32x4;

static __device__ __forceinline__ short f2bf(float f) {
    union { __hip_bfloat16 h; short s; } u;
    u.h = __float2bfloat16(f);
    return u.s;
}

static __device__ __forceinline__ bf16x8 cvt8(f32x4 a, f32x4 b) {
    bf16x8 r;
    r[0] = f2bf(a.x); r[1] = f2bf(a.y); r[2] = f2bf(a.z); r[3] = f2bf(a.w);
    r[4] = f2bf(b.x); r[5] = f2bf(b.y); r[6] = f2bf(b.z); r[7] = f2bf(b.w);
    return r;
}

__global__ __launch_bounds__(THREADS, 4) void mtal_mfma(
    const float* __restrict__ x, const int* __restrict__ tids,
    const float* __restrict__ emb, float* __restrict__ out, int B)
{
    __shared__ int rows[MAXB];
    __shared__ int cnt;

    const int t   = blockIdx.x >> 4;    // task id
    const int ct  = blockIdx.x & 15;    // col tile (16 outputs)
    const int tid = threadIdx.x;

    if (tid == 0) cnt = 0;
    __syncthreads();

    // Compact row list for task t into LDS (order irrelevant).
    for (int i = tid * 4; i < B; i += THREADS * 4) {
        int4 v = *reinterpret_cast<const int4*>(tids + i);
        if (v.x == t) rows[atomicAdd(&cnt, 1)] = i;
        if (v.y == t) rows[atomicAdd(&cnt, 1)] = i + 1;
        if (v.z == t) rows[atomicAdd(&cnt, 1)] = i + 2;
        if (v.w == t) rows[atomicAdd(&cnt, 1)] = i + 3;
    }
    __syncthreads();

    const int n = cnt;
    if (n == 0) return;

    const int lane  = tid & 63;
    const int wv    = tid >> 6;         // wave 0..3 (splits row tiles)
    const int l15   = lane & 15;        // A-row within tile == B-col within tile
    const int khalf = lane >> 4;        // 0..3, k-subgroup
    const int col   = ct * 16 + l15;

    const float* __restrict__ wbase = emb + (size_t)t * FULL_EMBED;

    // B fragments: W[col][k], k = ks*32 + khalf*8 + j. 32B contiguous per lane.
    const float* __restrict__ wp = wbase + (size_t)col * IN_CH + khalf * 8;
    bf16x8 wf[8];
#pragma unroll
    for (int ks = 0; ks < 8; ++ks) {
        f32x4 a = *reinterpret_cast<const f32x4*>(wp + ks * 32);
        f32x4 b = *reinterpret_cast<const f32x4*>(wp + ks * 32 + 4);
        wf[ks] = cvt8(a, b);
    }
    const float biasv = wbase[W_SIZE + col];

    const int nt = (n + 15) >> 4;       // row tiles of 16
    for (int rt = wv; rt < nt; rt += 4) {
        const int ridx = rt * 16 + l15;
        const int row  = rows[ridx < n ? ridx : 0];   // clamp dup for tail
        const float* __restrict__ xr = x + (size_t)row * IN_CH + khalf * 8;

        // A fragments: X[row][k], same k pattern as B.
        bf16x8 af[8];
#pragma unroll
        for (int ks = 0; ks < 8; ++ks) {
            f32x4 a = *reinterpret_cast<const f32x4*>(xr + ks * 32);
            f32x4 b = *reinterpret_cast<const f32x4*>(xr + ks * 32 + 4);
            af[ks] = cvt8(a, b);
        }

        f32x4 acc = { biasv, biasv, biasv, biasv };
#pragma unroll
        for (int ks = 0; ks < 8; ++ks)
            acc = __builtin_amdgcn_mfma_f32_16x16x32_bf16(af[ks], wf[ks], acc, 0, 0, 0);

        // D layout: col = lane&15, row = khalf*4 + reg (verified m89 mapping).
        const int m0 = rt * 16 + khalf * 4;
#pragma unroll
        for (int r = 0; r < 4; ++r) {
            const int gm = m0 + r;
            if (gm < n)
                out[(size_t)rows[gm] * OUT_CH + col] = acc[r];
        }
    }
}

extern "C" void kernel_launch(void* const* d_in, const int* in_sizes, int n_in,
                              void* d_out, int out_size, void* d_ws, size_t ws_size,
                              hipStream_t stream) {
    const float* x    = (const float*)d_in[0];
    const int*   tids = (const int*)d_in[1];
    const float* emb  = (const float*)d_in[2];
    float*       out  = (float*)d_out;
    const int B = in_sizes[1];   // 4096

    mtal_mfma<<<dim3(N_TASKS * NCOLT), dim3(THREADS), 0, stream>>>(
        x, tids, emb, out, B);
}